// Round 16
// baseline (255.826 us; speedup 1.0000x reference)
//
#include <hip/hip_runtime.h>
#include <hip/hip_bf16.h>

#define EPSB 1e-5f

typedef __hip_bfloat16 bf16;
typedef __attribute__((ext_vector_type(8))) short bf16x8;
typedef __attribute__((ext_vector_type(4))) float f32x4;

__device__ __forceinline__ unsigned short f2bu(float x) {
  bf16 h = __float2bfloat16(x);
  return *reinterpret_cast<unsigned short*>(&h);
}
__device__ __forceinline__ unsigned int pk2(float lo, float hi) {
  return ((unsigned int)f2bu(hi) << 16) | (unsigned int)f2bu(lo);
}

// ---------------- fused dual grouped 3x3 conv (both blocks), bf16 outputs.
// wcvt folded in as blockIdx.y==4 role. v19 vectorized stencil reads kept.
__global__ __launch_bounds__(256) void k_dwconv3(
    const float* __restrict__ x1, const float* __restrict__ x2,
    const float* __restrict__ w1, const float* __restrict__ b1,
    const float* __restrict__ w2, const float* __restrict__ b2,
    const float* __restrict__ w1pw, const float* __restrict__ w2pw,
    bf16* __restrict__ h1, bf16* __restrict__ h2,
    bf16* __restrict__ o1, bf16* __restrict__ o2) {
  if (blockIdx.y == 4) {           // wcvt role: 131072 floats each weight
    int x = blockIdx.x;
    if (x < 128) {
      int i = (x * 256 + threadIdx.x) * 4;
      float4 a = *(const float4*)(w1pw + i);
      float4 c = *(const float4*)(w2pw + i);
      uint2 ua = {pk2(a.x, a.y), pk2(a.z, a.w)};
      uint2 uc = {pk2(c.x, c.y), pk2(c.z, c.w)};
      *(uint2*)&o1[i] = ua;
      *(uint2*)&o2[i] = uc;
    }
    return;
  }

  __shared__ float img[2 * 64 * 64];
  int g = blockIdx.x, b = blockIdx.y;
  int t = threadIdx.x;
  int row = t >> 2, x0 = (t & 3) * 16;
  bool xlo = (x0 == 0), xhi = (x0 == 48);
  size_t obase = (((size_t)(b * 512 + 2 * g)) << 12) + row * 64 + x0;

  auto stencil = [&](const float* wp, float bs0, float bs1, bf16* hout) {
    float o0[16], o1v[16];
#pragma unroll
    for (int i = 0; i < 16; i++) { o0[i] = bs0; o1v[i] = bs1; }
#pragma unroll
    for (int ch = 0; ch < 2; ch++) {
      float wa[9], wb[9];
#pragma unroll
      for (int i = 0; i < 9; i++) { wa[i] = wp[ch * 9 + i]; wb[i] = wp[18 + ch * 9 + i]; }
      const float* ib = img + ch * 4096;
#pragma unroll
      for (int ky = 0; ky < 3; ky++) {
        int yy = row + ky - 1;
        if (yy < 0 || yy > 63) continue;
        const float* rp = ib + yy * 64 + x0;   // 16B-aligned
        float4 q0 = *(const float4*)(rp);
        float4 q1 = *(const float4*)(rp + 4);
        float4 q2 = *(const float4*)(rp + 8);
        float4 q3 = *(const float4*)(rp + 12);
        float v[18];
        v[0] = xlo ? 0.f : rp[-1];
        v[1] = q0.x;  v[2] = q0.y;  v[3] = q0.z;  v[4] = q0.w;
        v[5] = q1.x;  v[6] = q1.y;  v[7] = q1.z;  v[8] = q1.w;
        v[9] = q2.x;  v[10] = q2.y; v[11] = q2.z; v[12] = q2.w;
        v[13] = q3.x; v[14] = q3.y; v[15] = q3.z; v[16] = q3.w;
        v[17] = xhi ? 0.f : rp[16];
        float a0 = wa[ky * 3], a1 = wa[ky * 3 + 1], a2 = wa[ky * 3 + 2];
        float c0 = wb[ky * 3], c1 = wb[ky * 3 + 1], c2 = wb[ky * 3 + 2];
#pragma unroll
        for (int i = 0; i < 16; i++) {
          o0[i] += a0 * v[i] + a1 * v[i + 1] + a2 * v[i + 2];
          o1v[i] += c0 * v[i] + c1 * v[i + 1] + c2 * v[i + 2];
        }
      }
    }
    uint4 u0 = {pk2(o0[0], o0[1]), pk2(o0[2], o0[3]), pk2(o0[4], o0[5]), pk2(o0[6], o0[7])};
    uint4 u1 = {pk2(o0[8], o0[9]), pk2(o0[10], o0[11]), pk2(o0[12], o0[13]), pk2(o0[14], o0[15])};
    *(uint4*)&hout[obase] = u0;
    *(uint4*)&hout[obase + 8] = u1;
    uint4 w0 = {pk2(o1v[0], o1v[1]), pk2(o1v[2], o1v[3]), pk2(o1v[4], o1v[5]), pk2(o1v[6], o1v[7])};
    uint4 w1v = {pk2(o1v[8], o1v[9]), pk2(o1v[10], o1v[11]), pk2(o1v[12], o1v[13]), pk2(o1v[14], o1v[15])};
    *(uint4*)&hout[obase + 4096] = w0;
    *(uint4*)&hout[obase + 4096 + 8] = w1v;
  };

  if (g < 128) {
    const float4* p1 = (const float4*)(x1 + ((size_t)(b * 256 + 2 * g) << 12));
    const float4* p2 = (const float4*)(x2 + ((size_t)(b * 256 + 2 * g) << 12));
#pragma unroll
    for (int u = 0; u < 8; u++) {
      int i = u * 256 + t;
      float4 a = p1[i], c = p2[i];
      float4 d = {a.x - c.x, a.y - c.y, a.z - c.z, a.w - c.w};
      ((float4*)img)[i] = d;
    }
  } else {
    const float4* p1 = (const float4*)(x1 + ((size_t)(b * 256 + 2 * (g - 128)) << 12));
#pragma unroll
    for (int u = 0; u < 8; u++) {
      int i = u * 256 + t;
      ((float4*)img)[i] = p1[i];
    }
  }
  __syncthreads();
  stencil(w1 + (size_t)(2 * g) * 18, b1[2 * g], b1[2 * g + 1], h1);

  if (g >= 128) {
    __syncthreads();
    const float4* p2 = (const float4*)(x2 + ((size_t)(b * 256 + 2 * (g - 128)) << 12));
#pragma unroll
    for (int u = 0; u < 8; u++) {
      int i = u * 256 + t;
      ((float4*)img)[i] = p2[i];
    }
    __syncthreads();
  }
  stencil(w2 + (size_t)(2 * g) * 18, b2[2 * g], b2[2 * g + 1], h2);
}

// --------------- fused dual pointwise GEMM (both blocks), IC=512, bn+relu.
// v21 = v20 (2-phase reg-staged pipeline, verified R15) + T5 setprio around
// the MFMA cluster: 2 co-resident blocks/CU at different phases + in-phase
// load/MFMA role split -> scheduler can favor the MFMA-entering wave
// (mechanism that paid on attn, R4). Hint only — numerics untouched.
__global__ __launch_bounds__(256) void k_gemm_pw2(
    const bf16* __restrict__ In1, const bf16* __restrict__ In2,
    const bf16* __restrict__ W1, const bf16* __restrict__ W2,
    const float* __restrict__ bias1, const float* __restrict__ bias2,
    const float* __restrict__ g1v, const float* __restrict__ be1,
    const float* __restrict__ m1v, const float* __restrict__ v1v,
    const float* __restrict__ g2v, const float* __restrict__ be2,
    const float* __restrict__ m2v, const float* __restrict__ v2v,
    bf16* __restrict__ Out1, bf16* __restrict__ Out2) {
  __shared__ __align__(16) bf16 Al[2][128][72];
  __shared__ __align__(16) bf16 Bl[2][128][72];

  int lin = (blockIdx.z * 2 + blockIdx.y) * 32 + blockIdx.x;
  int xcd = lin & 7, slot = lin >> 3;       // bijective: 512 = 8 * 64
  int sel = xcd >> 2, b = xcd & 3;
  int p0 = (slot & 31) * 128;
  int oc0 = (slot >> 5) * 128;

  const bf16* In    = sel ? In2 : In1;
  const bf16* W     = sel ? W2 : W1;
  const float* bias = sel ? bias2 : bias1;
  const float* bng  = sel ? g2v : g1v;
  const float* bnb  = sel ? be2 : be1;
  const float* bnm  = sel ? m2v : m1v;
  const float* bnv  = sel ? v2v : v1v;
  bf16* Out         = sel ? Out2 : Out1;

  int t = threadIdx.x;
  int w = t >> 6, lane = t & 63, l16 = lane & 15, quad = lane >> 4;
  int wr = w >> 1, wc = w & 1;
  const bf16* Inb = In + (size_t)b * 512 * 4096;

  f32x4 acc[4][4];
#pragma unroll
  for (int mi = 0; mi < 4; mi++)
#pragma unroll
    for (int nj = 0; nj < 4; nj++) acc[mi][nj] = (f32x4){0.f, 0.f, 0.f, 0.f};

  int ocl = t >> 1, kb = (t & 1) * 32;
  int sch = t >> 2, soct = sch >> 3, swi = sch & 7, spg4 = t & 3;

  uint4 wreg0, wreg1, wreg2, wreg3, ireg0, ireg1, ireg2, ireg3;

  auto load_regs = [&](int kc) {
    const bf16* srcW = W + (size_t)(oc0 + ocl) * 512 + kc + kb;
    wreg0 = *(const uint4*)(srcW);
    wreg1 = *(const uint4*)(srcW + 8);
    wreg2 = *(const uint4*)(srcW + 16);
    wreg3 = *(const uint4*)(srcW + 24);
    const bf16* srcI = Inb + (size_t)(kc + sch) * 4096 + p0 + spg4 * 32;
    ireg0 = *(const uint4*)(srcI);
    ireg1 = *(const uint4*)(srcI + 8);
    ireg2 = *(const uint4*)(srcI + 16);
    ireg3 = *(const uint4*)(srcI + 24);
  };

  auto store_lds = [&](int pb) {
    *(uint4*)&Al[pb][ocl][kb] = wreg0;
    *(uint4*)&Al[pb][ocl][kb + 8] = wreg1;
    *(uint4*)&Al[pb][ocl][kb + 16] = wreg2;
    *(uint4*)&Al[pb][ocl][kb + 24] = wreg3;
    const uint4 iregs[4] = {ireg0, ireg1, ireg2, ireg3};
#pragma unroll
    for (int u = 0; u < 4; u++) {
      const unsigned short* qs = (const unsigned short*)&iregs[u];
      int pixb = spg4 * 32 + u * 8;
      int col = (((soct ^ (pixb >> 3)) & 7) << 3) | swi;
#pragma unroll
      for (int j = 0; j < 8; j++)
        *(unsigned short*)&Bl[pb][pixb + j][col] = qs[j];
    }
  };

  load_regs(0);
  store_lds(0);
  __syncthreads();

  for (int tt = 0; tt < 8; tt++) {
    int cur = tt & 1;
    if (tt < 7) {
      load_regs((tt + 1) * 64);
      __builtin_amdgcn_sched_barrier(0);   // pin load issue before compute
    }
#pragma unroll
    for (int h = 0; h < 2; h++) {
      bf16x8 af[4], bv[4];
#pragma unroll
      for (int mi = 0; mi < 4; mi++)
        af[mi] = *(const bf16x8*)&Al[cur][wr * 64 + mi * 16 + l16][h * 32 + quad * 8];
#pragma unroll
      for (int nj = 0; nj < 4; nj++) {
        int s = (nj * 2 + (l16 >> 3)) & 7;
        bv[nj] = *(const bf16x8*)&Bl[cur][wc * 64 + nj * 16 + l16][(((h * 4 + quad) ^ s) & 7) * 8];
      }
      __builtin_amdgcn_s_setprio(1);
#pragma unroll
      for (int mi = 0; mi < 4; mi++)
#pragma unroll
        for (int nj = 0; nj < 4; nj++)
          acc[mi][nj] = __builtin_amdgcn_mfma_f32_16x16x32_bf16(
              af[mi], bv[nj], acc[mi][nj], 0, 0, 0);
      __builtin_amdgcn_s_setprio(0);
    }
    if (tt < 7) store_lds(cur ^ 1);
    __syncthreads();
  }

#pragma unroll
  for (int mi = 0; mi < 4; mi++) {
    int ocb = oc0 + wr * 64 + mi * 16 + quad * 4;
    float4 bs4 = *(const float4*)&bias[ocb];
    float4 g4 = *(const float4*)&bng[ocb];
    float4 b4 = *(const float4*)&bnb[ocb];
    float4 m4 = *(const float4*)&bnm[ocb];
    float4 v4 = *(const float4*)&bnv[ocb];
    float sc[4], sh[4];
    sc[0] = g4.x * rsqrtf(v4.x + EPSB); sh[0] = bs4.x * sc[0] + b4.x - m4.x * sc[0];
    sc[1] = g4.y * rsqrtf(v4.y + EPSB); sh[1] = bs4.y * sc[1] + b4.y - m4.y * sc[1];
    sc[2] = g4.z * rsqrtf(v4.z + EPSB); sh[2] = bs4.z * sc[2] + b4.z - m4.z * sc[2];
    sc[3] = g4.w * rsqrtf(v4.w + EPSB); sh[3] = bs4.w * sc[3] + b4.w - m4.w * sc[3];
#pragma unroll
    for (int nj = 0; nj < 4; nj++) {
      int p = p0 + wc * 64 + nj * 16 + l16;
#pragma unroll
      for (int r = 0; r < 4; r++) {
        float val = fmaxf(acc[mi][nj][r] * sc[r] + sh[r], 0.f);
        Out[(((size_t)(b * 256 + ocb + r)) << 12) + p] = __float2bfloat16(val);
      }
    }
  }
}

// ---------------- merged V + QK GEMM, one launch. v21 = R14 + T5 setprio
// around MFMA clusters (same mechanism as pw2).
__global__ __launch_bounds__(256) void k_gemm_qkv(
    const bf16* __restrict__ x3, const bf16* __restrict__ x4,
    const float* __restrict__ wv, const float* __restrict__ bv,
    const float* __restrict__ wq, const float* __restrict__ wk,
    const float* __restrict__ bq, const float* __restrict__ bk,
    bf16* __restrict__ vvb, bf16* __restrict__ qbf, bf16* __restrict__ kbf) {
  __shared__ __align__(16) bf16 Al[128][72];
  __shared__ __align__(16) bf16 Bl[128][72];

  int lin = (blockIdx.z * 2 + blockIdx.y) * 64 + blockIdx.x;
  int xcd = lin & 7, slot = lin >> 3;       // slot in [0,64)
  int b = xcd >> 1;
  int idx = ((xcd & 1) * 64) + slot;        // [0,128)
  int by = idx >> 6;
  int bx = idx & 63;

  int t = threadIdx.x;
  int w = t >> 6, lane = t & 63, l16 = lane & 15, quad = lane >> 4;

  if (bx < 32) {
    // ------------------------------ V role (OC=256, IC=256, 128x128, BK=64)
    int wr = w >> 1, wc = w & 1;
    int p0 = bx * 128;
    int oc0 = by * 128;
    const bf16* Inb = x3 + (size_t)b * 256 * 4096;

    f32x4 acc[4][4];
#pragma unroll
    for (int mi = 0; mi < 4; mi++)
#pragma unroll
      for (int nj = 0; nj < 4; nj++) acc[mi][nj] = (f32x4){0.f, 0.f, 0.f, 0.f};

    int ocl = t >> 1, kb = (t & 1) * 32;
    int sch = t >> 2, soct = sch >> 3, swi = sch & 7, spg4 = t & 3;

    for (int kc = 0; kc < 256; kc += 64) {
      __syncthreads();
      {
        const float* src = wv + (size_t)(oc0 + ocl) * 256 + kc + kb;
#pragma unroll
        for (int u = 0; u < 4; u++) {
          float4 f0 = *(const float4*)(src + u * 8);
          float4 f1 = *(const float4*)(src + u * 8 + 4);
          uint4 uu = {pk2(f0.x, f0.y), pk2(f0.z, f0.w), pk2(f1.x, f1.y), pk2(f1.z, f1.w)};
          *(uint4*)&Al[ocl][kb + u * 8] = uu;
        }
      }
      {
        const bf16* src = Inb + (size_t)(kc + sch) * 4096 + p0 + spg4 * 32;
#pragma unroll
        for (int u = 0; u < 4; u++) {
          uint4 qv = *(const uint4*)(src + u * 8);
          const unsigned short* qs = (const unsigned short*)&qv;
          int pixb = spg4 * 32 + u * 8;
          int col = (((soct ^ (pixb >> 3)) & 7) << 3) | swi;
#pragma unroll
          for (int j = 0; j < 8; j++)
            *(unsigned short*)&Bl[pixb + j][col] = qs[j];
        }
      }
      __syncthreads();
#pragma unroll
      for (int h = 0; h < 2; h++) {
        bf16x8 af[4], bvv[4];
#pragma unroll
        for (int mi = 0; mi < 4; mi++)
          af[mi] = *(const bf16x8*)&Al[wr * 64 + mi * 16 + l16][h * 32 + quad * 8];
#pragma unroll
        for (int nj = 0; nj < 4; nj++) {
          int s = (nj * 2 + (l16 >> 3)) & 7;
          bvv[nj] = *(const bf16x8*)&Bl[wc * 64 + nj * 16 + l16][(((h * 4 + quad) ^ s) & 7) * 8];
        }
        __builtin_amdgcn_s_setprio(1);
#pragma unroll
        for (int mi = 0; mi < 4; mi++)
#pragma unroll
          for (int nj = 0; nj < 4; nj++)
            acc[mi][nj] = __builtin_amdgcn_mfma_f32_16x16x32_bf16(
                af[mi], bvv[nj], acc[mi][nj], 0, 0, 0);
        __builtin_amdgcn_s_setprio(0);
      }
    }

#pragma unroll
    for (int mi = 0; mi < 4; mi++) {
      int ocb = oc0 + wr * 64 + mi * 16 + quad * 4;
      float4 bs4 = *(const float4*)&bv[ocb];
      float sh[4] = {bs4.x, bs4.y, bs4.z, bs4.w};
#pragma unroll
      for (int nj = 0; nj < 4; nj++) {
        int p = p0 + wc * 64 + nj * 16 + l16;
#pragma unroll
        for (int r = 0; r < 4; r++) {
          float val = acc[mi][nj][r] + sh[r];
          vvb[(((size_t)(b * 256 + ocb + r)) << 12) + p] = __float2bfloat16(val);
        }
      }
    }
  } else {
    // ------------------------------ QK role (OC=32, IC=256)
    int p0 = (bx - 32) * 128;
    const bf16* In  = (by == 0) ? x4 : x3;
    const float* W  = (by == 0) ? wq : wk;
    const float* bi = (by == 0) ? bq : bk;
    bf16* Out       = (by == 0) ? qbf : kbf;
    const bf16* Inb = In + (size_t)b * 256 * 4096;

    f32x4 acc[2][2];
#pragma unroll
    for (int mi = 0; mi < 2; mi++)
#pragma unroll
      for (int nj = 0; nj < 2; nj++) acc[mi][nj] = (f32x4){0.f, 0.f, 0.f, 0.f};

    int aocl = t >> 3, akb = (t & 7) * 4;
    int sch = t >> 3, soct = sch >> 3, swi = sch & 7, spg = t & 7;

    for (int kc = 0; kc < 256; kc += 32) {
      __syncthreads();
      {
        const float* src = W + (size_t)aocl * 256 + kc + akb;
        float4 f0 = *(const float4*)(src);
        uint2 u = {pk2(f0.x, f0.y), pk2(f0.z, f0.w)};
        *(uint2*)&Al[aocl][akb] = u;
      }
      {
        const bf16* src = Inb + (size_t)(kc + sch) * 4096 + p0 + spg * 16;
        uint4 qv0 = *(const uint4*)src;
        uint4 qv1 = *(const uint4*)(src + 8);
        const unsigned short* qs0 = (const unsigned short*)&qv0;
        const unsigned short* qs1 = (const unsigned short*)&qv1;
#pragma unroll
        for (int j = 0; j < 8; j++) {
          int pix = spg * 16 + j;
          int col = (((soct ^ (pix >> 3)) & 3) << 3) | swi;
          *(unsigned short*)&Bl[pix][col] = qs0[j];
        }
#pragma unroll
        for (int j = 0; j < 8; j++) {
          int pix = spg * 16 + 8 + j;
          int col = (((soct ^ (pix >> 3)) & 3) << 3) | swi;
          *(unsigned short*)&Bl[pix][col] = qs1[j];
        }
      }
      __syncthreads();
      bf16x8 af[2], bvv[2];
#pragma unroll
      for (int mi = 0; mi < 2; mi++)
        af[mi] = *(const bf16x8*)&Al[mi * 16 + l16][quad * 8];
#pragma unroll
      for (int nj = 0; nj < 2; nj++) {
        int s = (nj * 2 + (l16 >> 3)) & 3;
        bvv[nj] = *(const bf16x8*)&Bl[w * 32 + nj * 16 + l16][(quad ^ s) * 8];
      }
      __builtin_amdgcn_s_setprio(1);
#pragma unroll
      for (int mi = 0; mi < 2; mi++)
#pragma unroll
        for (int nj = 0; nj < 2; nj++)
          acc[mi][nj] = __builtin_amdgcn_mfma_f32_16x16x32_bf16(
              af[mi], bvv[nj], acc[mi][nj], 0, 0, 0);
      __builtin_amdgcn_s_setprio(0);
    }

#pragma unroll
    for (int mi = 0; mi < 2; mi++) {
      int ocb = mi * 16 + quad * 4;
      float4 bs4 = *(const float4*)&bi[ocb];
      float bs[4] = {bs4.x, bs4.y, bs4.z, bs4.w};
#pragma unroll
      for (int nj = 0; nj < 2; nj++) {
        int p = p0 + w * 32 + nj * 16 + l16;
        float v0 = acc[mi][nj][0] + bs[0];
        float v1 = acc[mi][nj][1] + bs[1];
        float v2 = acc[mi][nj][2] + bs[2];
        float v3 = acc[mi][nj][3] + bs[3];
        uint2 u = {pk2(v0, v1), pk2(v2, v3)};
        *(uint2*)&Out[((size_t)(b * 4096) + p) * 32 + ocb] = u;
      }
    }
  }
}

// ------------------------------------------- MFMA flash attention + residual
// v10 structure + clamp removal (verified R13-R15: ~82us, VALUBusy 34%).
// UNTOUCHED. Signature: VGPR 60, occ ~40%, FETCH 14.4MB, conflicts 2.1M.
__global__ __launch_bounds__(512, 4) void k_attn_mfma(
    const bf16* __restrict__ qb, const bf16* __restrict__ kb,
    const bf16* __restrict__ vb, const float* __restrict__ x1,
    const float* __restrict__ gamma, float* __restrict__ out) {
  __shared__ __align__(16) bf16 Pl[2][64 * 128];   // 32 KB
  __shared__ float lsumw[8][64];

  int t = threadIdx.x;
  int w = t >> 6, lane = t & 63;
  int l16 = lane & 15, quad = lane >> 4;

  int lin = blockIdx.y * 128 + blockIdx.x;
  int xcd = lin & 7, slot = lin >> 3;
  int b = xcd >> 1;
  int chalf = xcd & 1;
  int q0 = slot * 64;

  const bf16* kbb = kb + (size_t)b * 4096 * 32;
  const bf16* vbb = vb + ((size_t)(b * 256 + chalf * 128)) * 4096;

  bf16x8 qf[4];
#pragma unroll
  for (int nj = 0; nj < 4; nj++)
    qf[nj] = *(const bf16x8*)(qb + ((size_t)(b * 4096 + q0 + nj * 16 + l16)) * 32 + quad * 8);

  f32x4 acc[4];
#pragma unroll
  for (int nj = 0; nj < 4; nj++) acc[nj] = (f32x4){0.f, 0.f, 0.f, 0.f};
  float lpart[4] = {0.f, 0.f, 0.f, 0.f};

  const bf16* kptr = kbb + ((size_t)(w * 16 + l16)) * 32 + quad * 8;
  const bf16* vptr = vbb + ((size_t)(w * 16 + l16)) * 4096 + quad * 8;

  int c16w = w * 2 + (quad >> 1);
  int off8 = (quad & 1) * 4;

  auto load_kv = [&](int j0, bf16x8& kf, bf16x8 vf[4]) {
    kf = *(const bf16x8*)(kptr + (size_t)j0 * 32);
#pragma unroll
    for (int kc = 0; kc < 4; kc++)
      vf[kc] = *(const bf16x8*)(vptr + j0 + kc * 32);
  };

  auto s_phase = [&](const bf16x8& kf, int pb) {
    bf16* P = Pl[pb];
    __builtin_amdgcn_s_setprio(1);
#pragma unroll
    for (int nj = 0; nj < 4; nj++) {
      f32x4 s = __builtin_amdgcn_mfma_f32_16x16x32_bf16(
          kf, qf[nj], (f32x4){0.f, 0.f, 0.f, 0.f}, 0, 0, 0);
      float p0f = __expf(s[0]);
      float p1f = __expf(s[1]);
      float p2f = __expf(s[2]);
      float p3f = __expf(s[3]);
      lpart[nj] += (p0f + p1f) + (p2f + p3f);
      int row = nj * 16 + l16;
      int c16 = c16w ^ (row & 15);
      uint2 u = {pk2(p0f, p1f), pk2(p2f, p3f)};
      *(uint2*)&P[row * 128 + c16 * 8 + off8] = u;
    }
    __builtin_amdgcn_s_setprio(0);
  };

  auto pv_phase = [&](const bf16x8 vf[4], int pb) {
    const bf16* P = Pl[pb];
#pragma unroll
    for (int kc = 0; kc < 4; kc++) {
      bf16x8 pf[4];
#pragma unroll
      for (int nj = 0; nj < 4; nj++) {
        int row = nj * 16 + l16;
        int c16 = (kc * 4 + quad) ^ (row & 15);
        pf[nj] = *(const bf16x8*)&P[row * 128 + c16 * 8];
      }
      __builtin_amdgcn_s_setprio(1);
#pragma unroll
      for (int nj = 0; nj < 4; nj++)
        acc[nj] = __builtin_amdgcn_mfma_f32_16x16x32_bf16(
            vf[kc], pf[nj], acc[nj], 0, 0, 0);
      __builtin_amdgcn_s_setprio(0);
    }
  };

  bf16x8 kfA, kfB, vfA[4], vfB[4];
  load_kv(0, kfA, vfA);
  s_phase(kfA, 0);

  for (int i = 0; i < 32; i += 2) {
    __syncthreads();
    if (i < 31) load_kv((i + 1) * 128, kfB, vfB);
    pv_phase(vfA, 0);
    if (i < 31) s_phase(kfB, 1);
    __syncthreads();
    if (i + 2 < 32) load_kv((i + 2) * 128, kfA, vfA);
    if (i + 1 < 32) pv_phase(vfB, 1);
    if (i + 2 < 32) s_phase(kfA, 0);
  }

#pragma unroll
  for (int nj = 0; nj < 4; nj++) {
    float v = lpart[nj];
    v += __shfl_xor(v, 16);
    v += __shfl_xor(v, 32);
    lpart[nj] = v;
  }
  if (lane < 16) {
#pragma unroll
    for (int nj = 0; nj < 4; nj++) lsumw[w][nj * 16 + lane] = lpart[nj];
  }
  __syncthreads();

  float gm = gamma[0];
#pragma unroll
  for (int nj = 0; nj < 4; nj++) {
    int ql = nj * 16 + l16;
    float ls = 0.f;
#pragma unroll
    for (int w8 = 0; w8 < 8; w8++) ls += lsumw[w8][ql];
    float gl = gm / ls;
    int cb = chalf * 128 + w * 16 + quad * 4;
#pragma unroll
    for (int r = 0; r < 4; r++) {
      size_t gidx = (((size_t)(b * 256 + cb + r)) << 12) + q0 + ql;
      out[gidx] = gl * acc[nj][r] + x1[gidx];
    }
  }
}

// ------------------------------------------------------------------- launcher
extern "C" void kernel_launch(void* const* d_in, const int* in_sizes, int n_in,
                              void* d_out, int out_size, void* d_ws, size_t ws_size,
                              hipStream_t stream) {
  const float* x1    = (const float*)d_in[0];
  const float* x2    = (const float*)d_in[1];
  const float* w1_dw = (const float*)d_in[2];
  const float* b1_dw = (const float*)d_in[3];
  const float* w1_pw = (const float*)d_in[4];
  const float* b1_pw = (const float*)d_in[5];
  const float* bn1_g = (const float*)d_in[6];
  const float* bn1_b = (const float*)d_in[7];
  const float* bn1_m = (const float*)d_in[8];
  const float* bn1_v = (const float*)d_in[9];
  const float* w2_dw = (const float*)d_in[10];
  const float* b2_dw = (const float*)d_in[11];
  const float* w2_pw = (const float*)d_in[12];
  const float* b2_pw = (const float*)d_in[13];
  const float* bn2_g = (const float*)d_in[14];
  const float* bn2_b = (const float*)d_in[15];
  const float* bn2_m = (const float*)d_in[16];
  const float* bn2_v = (const float*)d_in[17];
  const float* wq    = (const float*)d_in[18];
  const float* bq    = (const float*)d_in[19];
  const float* wk    = (const float*)d_in[20];
  const float* bk    = (const float*)d_in[21];
  const float* wv    = (const float*)d_in[22];
  const float* bv    = (const float*)d_in[23];
  const float* gamma = (const float*)d_in[24];

  // ws layout (bf16 units): h1 8.4M | h2 8.4M | x3 4.2M | x4 4.2M |
  // qb .5M | kb .5M | v 4.2M  -> 30.4M elems = 60.8 MB.
  // w1b/w2b live in the FRONT of the v region (written by dwconv3's wcvt
  // role, consumed by pw2, then overwritten by qkv's V role).
  bf16* wsb = (bf16*)d_ws;
  bf16* h1  = wsb;
  bf16* h2  = wsb + 8388608;
  bf16* x3  = wsb + 16777216;
  bf16* x4  = wsb + 20971520;
  bf16* qbf = wsb + 25165824;
  bf16* kbf = wsb + 25690112;
  bf16* vvb = wsb + 26214400;
  bf16* w1b = vvb;
  bf16* w2b = vvb + 131072;

  k_dwconv3<<<dim3(256, 5), 256, 0, stream>>>(x1, x2, w1_dw, b1_dw, w2_dw, b2_dw,
                                              w1_pw, w2_pw, h1, h2, w1b, w2b);
  k_gemm_pw2<<<dim3(32, 2, 8), 256, 0, stream>>>(h1, h2, w1b, w2b, b1_pw, b2_pw,
                                                 bn1_g, bn1_b, bn1_m, bn1_v,
                                                 bn2_g, bn2_b, bn2_m, bn2_v, x3, x4);
  k_gemm_qkv<<<dim3(64, 2, 4), 256, 0, stream>>>(x3, x4, wv, bv, wq, wk, bq, bk,
                                                 vvb, qbf, kbf);
  k_attn_mfma<<<dim3(128, 4), 512, 0, stream>>>(qbf, kbf, vvb, x1, gamma, (float*)d_out);
}

// Round 17
// 251.452 us; speedup vs baseline: 1.0174x; 1.0174x over previous
//
#include <hip/hip_runtime.h>
#include <hip/hip_bf16.h>

#define EPSB 1e-5f

typedef __hip_bfloat16 bf16;
typedef __attribute__((ext_vector_type(8))) short bf16x8;
typedef __attribute__((ext_vector_type(4))) float f32x4;

__device__ __forceinline__ unsigned short f2bu(float x) {
  bf16 h = __float2bfloat16(x);
  return *reinterpret_cast<unsigned short*>(&h);
}
__device__ __forceinline__ unsigned int pk2(float lo, float hi) {
  return ((unsigned int)f2bu(hi) << 16) | (unsigned int)f2bu(lo);
}

// ---------------- fused dual grouped 3x3 conv (both blocks), bf16 outputs.
// wcvt folded in as blockIdx.y==4 role. v19 vectorized stencil reads kept.
__global__ __launch_bounds__(256) void k_dwconv3(
    const float* __restrict__ x1, const float* __restrict__ x2,
    const float* __restrict__ w1, const float* __restrict__ b1,
    const float* __restrict__ w2, const float* __restrict__ b2,
    const float* __restrict__ w1pw, const float* __restrict__ w2pw,
    bf16* __restrict__ h1, bf16* __restrict__ h2,
    bf16* __restrict__ o1, bf16* __restrict__ o2) {
  if (blockIdx.y == 4) {           // wcvt role: 131072 floats each weight
    int x = blockIdx.x;
    if (x < 128) {
      int i = (x * 256 + threadIdx.x) * 4;
      float4 a = *(const float4*)(w1pw + i);
      float4 c = *(const float4*)(w2pw + i);
      uint2 ua = {pk2(a.x, a.y), pk2(a.z, a.w)};
      uint2 uc = {pk2(c.x, c.y), pk2(c.z, c.w)};
      *(uint2*)&o1[i] = ua;
      *(uint2*)&o2[i] = uc;
    }
    return;
  }

  __shared__ float img[2 * 64 * 64];
  int g = blockIdx.x, b = blockIdx.y;
  int t = threadIdx.x;
  int row = t >> 2, x0 = (t & 3) * 16;
  bool xlo = (x0 == 0), xhi = (x0 == 48);
  size_t obase = (((size_t)(b * 512 + 2 * g)) << 12) + row * 64 + x0;

  auto stencil = [&](const float* wp, float bs0, float bs1, bf16* hout) {
    float o0[16], o1v[16];
#pragma unroll
    for (int i = 0; i < 16; i++) { o0[i] = bs0; o1v[i] = bs1; }
#pragma unroll
    for (int ch = 0; ch < 2; ch++) {
      float wa[9], wb[9];
#pragma unroll
      for (int i = 0; i < 9; i++) { wa[i] = wp[ch * 9 + i]; wb[i] = wp[18 + ch * 9 + i]; }
      const float* ib = img + ch * 4096;
#pragma unroll
      for (int ky = 0; ky < 3; ky++) {
        int yy = row + ky - 1;
        if (yy < 0 || yy > 63) continue;
        const float* rp = ib + yy * 64 + x0;   // 16B-aligned
        float4 q0 = *(const float4*)(rp);
        float4 q1 = *(const float4*)(rp + 4);
        float4 q2 = *(const float4*)(rp + 8);
        float4 q3 = *(const float4*)(rp + 12);
        float v[18];
        v[0] = xlo ? 0.f : rp[-1];
        v[1] = q0.x;  v[2] = q0.y;  v[3] = q0.z;  v[4] = q0.w;
        v[5] = q1.x;  v[6] = q1.y;  v[7] = q1.z;  v[8] = q1.w;
        v[9] = q2.x;  v[10] = q2.y; v[11] = q2.z; v[12] = q2.w;
        v[13] = q3.x; v[14] = q3.y; v[15] = q3.z; v[16] = q3.w;
        v[17] = xhi ? 0.f : rp[16];
        float a0 = wa[ky * 3], a1 = wa[ky * 3 + 1], a2 = wa[ky * 3 + 2];
        float c0 = wb[ky * 3], c1 = wb[ky * 3 + 1], c2 = wb[ky * 3 + 2];
#pragma unroll
        for (int i = 0; i < 16; i++) {
          o0[i] += a0 * v[i] + a1 * v[i + 1] + a2 * v[i + 2];
          o1v[i] += c0 * v[i] + c1 * v[i + 1] + c2 * v[i + 2];
        }
      }
    }
    uint4 u0 = {pk2(o0[0], o0[1]), pk2(o0[2], o0[3]), pk2(o0[4], o0[5]), pk2(o0[6], o0[7])};
    uint4 u1 = {pk2(o0[8], o0[9]), pk2(o0[10], o0[11]), pk2(o0[12], o0[13]), pk2(o0[14], o0[15])};
    *(uint4*)&hout[obase] = u0;
    *(uint4*)&hout[obase + 8] = u1;
    uint4 w0 = {pk2(o1v[0], o1v[1]), pk2(o1v[2], o1v[3]), pk2(o1v[4], o1v[5]), pk2(o1v[6], o1v[7])};
    uint4 w1v = {pk2(o1v[8], o1v[9]), pk2(o1v[10], o1v[11]), pk2(o1v[12], o1v[13]), pk2(o1v[14], o1v[15])};
    *(uint4*)&hout[obase + 4096] = w0;
    *(uint4*)&hout[obase + 4096 + 8] = w1v;
  };

  if (g < 128) {
    const float4* p1 = (const float4*)(x1 + ((size_t)(b * 256 + 2 * g) << 12));
    const float4* p2 = (const float4*)(x2 + ((size_t)(b * 256 + 2 * g) << 12));
#pragma unroll
    for (int u = 0; u < 8; u++) {
      int i = u * 256 + t;
      float4 a = p1[i], c = p2[i];
      float4 d = {a.x - c.x, a.y - c.y, a.z - c.z, a.w - c.w};
      ((float4*)img)[i] = d;
    }
  } else {
    const float4* p1 = (const float4*)(x1 + ((size_t)(b * 256 + 2 * (g - 128)) << 12));
#pragma unroll
    for (int u = 0; u < 8; u++) {
      int i = u * 256 + t;
      ((float4*)img)[i] = p1[i];
    }
  }
  __syncthreads();
  stencil(w1 + (size_t)(2 * g) * 18, b1[2 * g], b1[2 * g + 1], h1);

  if (g >= 128) {
    __syncthreads();
    const float4* p2 = (const float4*)(x2 + ((size_t)(b * 256 + 2 * (g - 128)) << 12));
#pragma unroll
    for (int u = 0; u < 8; u++) {
      int i = u * 256 + t;
      ((float4*)img)[i] = p2[i];
    }
    __syncthreads();
  }
  stencil(w2 + (size_t)(2 * g) * 18, b2[2 * g], b2[2 * g + 1], h2);
}

// --------------- fused dual pointwise GEMM (both blocks), IC=512, bn+relu.
// v20 (verified R15): 2-phase reg-staged pipeline, BK=64, [2][128][72] LDS,
// one barrier per tile, 8-octet XOR swizzle. FINAL.
__global__ __launch_bounds__(256) void k_gemm_pw2(
    const bf16* __restrict__ In1, const bf16* __restrict__ In2,
    const bf16* __restrict__ W1, const bf16* __restrict__ W2,
    const float* __restrict__ bias1, const float* __restrict__ bias2,
    const float* __restrict__ g1v, const float* __restrict__ be1,
    const float* __restrict__ m1v, const float* __restrict__ v1v,
    const float* __restrict__ g2v, const float* __restrict__ be2,
    const float* __restrict__ m2v, const float* __restrict__ v2v,
    bf16* __restrict__ Out1, bf16* __restrict__ Out2) {
  __shared__ __align__(16) bf16 Al[2][128][72];
  __shared__ __align__(16) bf16 Bl[2][128][72];

  int lin = (blockIdx.z * 2 + blockIdx.y) * 32 + blockIdx.x;
  int xcd = lin & 7, slot = lin >> 3;       // bijective: 512 = 8 * 64
  int sel = xcd >> 2, b = xcd & 3;
  int p0 = (slot & 31) * 128;
  int oc0 = (slot >> 5) * 128;

  const bf16* In    = sel ? In2 : In1;
  const bf16* W     = sel ? W2 : W1;
  const float* bias = sel ? bias2 : bias1;
  const float* bng  = sel ? g2v : g1v;
  const float* bnb  = sel ? be2 : be1;
  const float* bnm  = sel ? m2v : m1v;
  const float* bnv  = sel ? v2v : v1v;
  bf16* Out         = sel ? Out2 : Out1;

  int t = threadIdx.x;
  int w = t >> 6, lane = t & 63, l16 = lane & 15, quad = lane >> 4;
  int wr = w >> 1, wc = w & 1;
  const bf16* Inb = In + (size_t)b * 512 * 4096;

  f32x4 acc[4][4];
#pragma unroll
  for (int mi = 0; mi < 4; mi++)
#pragma unroll
    for (int nj = 0; nj < 4; nj++) acc[mi][nj] = (f32x4){0.f, 0.f, 0.f, 0.f};

  int ocl = t >> 1, kb = (t & 1) * 32;
  int sch = t >> 2, soct = sch >> 3, swi = sch & 7, spg4 = t & 3;

  uint4 wreg0, wreg1, wreg2, wreg3, ireg0, ireg1, ireg2, ireg3;

  auto load_regs = [&](int kc) {
    const bf16* srcW = W + (size_t)(oc0 + ocl) * 512 + kc + kb;
    wreg0 = *(const uint4*)(srcW);
    wreg1 = *(const uint4*)(srcW + 8);
    wreg2 = *(const uint4*)(srcW + 16);
    wreg3 = *(const uint4*)(srcW + 24);
    const bf16* srcI = Inb + (size_t)(kc + sch) * 4096 + p0 + spg4 * 32;
    ireg0 = *(const uint4*)(srcI);
    ireg1 = *(const uint4*)(srcI + 8);
    ireg2 = *(const uint4*)(srcI + 16);
    ireg3 = *(const uint4*)(srcI + 24);
  };

  auto store_lds = [&](int pb) {
    *(uint4*)&Al[pb][ocl][kb] = wreg0;
    *(uint4*)&Al[pb][ocl][kb + 8] = wreg1;
    *(uint4*)&Al[pb][ocl][kb + 16] = wreg2;
    *(uint4*)&Al[pb][ocl][kb + 24] = wreg3;
    const uint4 iregs[4] = {ireg0, ireg1, ireg2, ireg3};
#pragma unroll
    for (int u = 0; u < 4; u++) {
      const unsigned short* qs = (const unsigned short*)&iregs[u];
      int pixb = spg4 * 32 + u * 8;
      int col = (((soct ^ (pixb >> 3)) & 7) << 3) | swi;
#pragma unroll
      for (int j = 0; j < 8; j++)
        *(unsigned short*)&Bl[pb][pixb + j][col] = qs[j];
    }
  };

  load_regs(0);
  store_lds(0);
  __syncthreads();

  for (int tt = 0; tt < 8; tt++) {
    int cur = tt & 1;
    if (tt < 7) {
      load_regs((tt + 1) * 64);
      __builtin_amdgcn_sched_barrier(0);   // pin load issue before compute
    }
#pragma unroll
    for (int h = 0; h < 2; h++) {
      bf16x8 af[4], bv[4];
#pragma unroll
      for (int mi = 0; mi < 4; mi++)
        af[mi] = *(const bf16x8*)&Al[cur][wr * 64 + mi * 16 + l16][h * 32 + quad * 8];
#pragma unroll
      for (int nj = 0; nj < 4; nj++) {
        int s = (nj * 2 + (l16 >> 3)) & 7;
        bv[nj] = *(const bf16x8*)&Bl[cur][wc * 64 + nj * 16 + l16][(((h * 4 + quad) ^ s) & 7) * 8];
      }
#pragma unroll
      for (int mi = 0; mi < 4; mi++)
#pragma unroll
        for (int nj = 0; nj < 4; nj++)
          acc[mi][nj] = __builtin_amdgcn_mfma_f32_16x16x32_bf16(
              af[mi], bv[nj], acc[mi][nj], 0, 0, 0);
    }
    if (tt < 7) store_lds(cur ^ 1);
    __syncthreads();
  }

#pragma unroll
  for (int mi = 0; mi < 4; mi++) {
    int ocb = oc0 + wr * 64 + mi * 16 + quad * 4;
    float4 bs4 = *(const float4*)&bias[ocb];
    float4 g4 = *(const float4*)&bng[ocb];
    float4 b4 = *(const float4*)&bnb[ocb];
    float4 m4 = *(const float4*)&bnm[ocb];
    float4 v4 = *(const float4*)&bnv[ocb];
    float sc[4], sh[4];
    sc[0] = g4.x * rsqrtf(v4.x + EPSB); sh[0] = bs4.x * sc[0] + b4.x - m4.x * sc[0];
    sc[1] = g4.y * rsqrtf(v4.y + EPSB); sh[1] = bs4.y * sc[1] + b4.y - m4.y * sc[1];
    sc[2] = g4.z * rsqrtf(v4.z + EPSB); sh[2] = bs4.z * sc[2] + b4.z - m4.z * sc[2];
    sc[3] = g4.w * rsqrtf(v4.w + EPSB); sh[3] = bs4.w * sc[3] + b4.w - m4.w * sc[3];
#pragma unroll
    for (int nj = 0; nj < 4; nj++) {
      int p = p0 + wc * 64 + nj * 16 + l16;
#pragma unroll
      for (int r = 0; r < 4; r++) {
        float val = fmaxf(acc[mi][nj][r] * sc[r] + sh[r], 0.f);
        Out[(((size_t)(b * 256 + ocb + r)) << 12) + p] = __float2bfloat16(val);
      }
    }
  }
}

// ---------------- merged V + QK GEMM, one launch (verified R14/R15). FINAL.
__global__ __launch_bounds__(256) void k_gemm_qkv(
    const bf16* __restrict__ x3, const bf16* __restrict__ x4,
    const float* __restrict__ wv, const float* __restrict__ bv,
    const float* __restrict__ wq, const float* __restrict__ wk,
    const float* __restrict__ bq, const float* __restrict__ bk,
    bf16* __restrict__ vvb, bf16* __restrict__ qbf, bf16* __restrict__ kbf) {
  __shared__ __align__(16) bf16 Al[128][72];
  __shared__ __align__(16) bf16 Bl[128][72];

  int lin = (blockIdx.z * 2 + blockIdx.y) * 64 + blockIdx.x;
  int xcd = lin & 7, slot = lin >> 3;       // slot in [0,64)
  int b = xcd >> 1;
  int idx = ((xcd & 1) * 64) + slot;        // [0,128)
  int by = idx >> 6;
  int bx = idx & 63;

  int t = threadIdx.x;
  int w = t >> 6, lane = t & 63, l16 = lane & 15, quad = lane >> 4;

  if (bx < 32) {
    // ------------------------------ V role (OC=256, IC=256, 128x128, BK=64)
    int wr = w >> 1, wc = w & 1;
    int p0 = bx * 128;
    int oc0 = by * 128;
    const bf16* Inb = x3 + (size_t)b * 256 * 4096;

    f32x4 acc[4][4];
#pragma unroll
    for (int mi = 0; mi < 4; mi++)
#pragma unroll
      for (int nj = 0; nj < 4; nj++) acc[mi][nj] = (f32x4){0.f, 0.f, 0.f, 0.f};

    int ocl = t >> 1, kb = (t & 1) * 32;
    int sch = t >> 2, soct = sch >> 3, swi = sch & 7, spg4 = t & 3;

    for (int kc = 0; kc < 256; kc += 64) {
      __syncthreads();
      {
        const float* src = wv + (size_t)(oc0 + ocl) * 256 + kc + kb;
#pragma unroll
        for (int u = 0; u < 4; u++) {
          float4 f0 = *(const float4*)(src + u * 8);
          float4 f1 = *(const float4*)(src + u * 8 + 4);
          uint4 uu = {pk2(f0.x, f0.y), pk2(f0.z, f0.w), pk2(f1.x, f1.y), pk2(f1.z, f1.w)};
          *(uint4*)&Al[ocl][kb + u * 8] = uu;
        }
      }
      {
        const bf16* src = Inb + (size_t)(kc + sch) * 4096 + p0 + spg4 * 32;
#pragma unroll
        for (int u = 0; u < 4; u++) {
          uint4 qv = *(const uint4*)(src + u * 8);
          const unsigned short* qs = (const unsigned short*)&qv;
          int pixb = spg4 * 32 + u * 8;
          int col = (((soct ^ (pixb >> 3)) & 7) << 3) | swi;
#pragma unroll
          for (int j = 0; j < 8; j++)
            *(unsigned short*)&Bl[pixb + j][col] = qs[j];
        }
      }
      __syncthreads();
#pragma unroll
      for (int h = 0; h < 2; h++) {
        bf16x8 af[4], bvv[4];
#pragma unroll
        for (int mi = 0; mi < 4; mi++)
          af[mi] = *(const bf16x8*)&Al[wr * 64 + mi * 16 + l16][h * 32 + quad * 8];
#pragma unroll
        for (int nj = 0; nj < 4; nj++) {
          int s = (nj * 2 + (l16 >> 3)) & 7;
          bvv[nj] = *(const bf16x8*)&Bl[wc * 64 + nj * 16 + l16][(((h * 4 + quad) ^ s) & 7) * 8];
        }
#pragma unroll
        for (int mi = 0; mi < 4; mi++)
#pragma unroll
          for (int nj = 0; nj < 4; nj++)
            acc[mi][nj] = __builtin_amdgcn_mfma_f32_16x16x32_bf16(
                af[mi], bvv[nj], acc[mi][nj], 0, 0, 0);
      }
    }

#pragma unroll
    for (int mi = 0; mi < 4; mi++) {
      int ocb = oc0 + wr * 64 + mi * 16 + quad * 4;
      float4 bs4 = *(const float4*)&bv[ocb];
      float sh[4] = {bs4.x, bs4.y, bs4.z, bs4.w};
#pragma unroll
      for (int nj = 0; nj < 4; nj++) {
        int p = p0 + wc * 64 + nj * 16 + l16;
#pragma unroll
        for (int r = 0; r < 4; r++) {
          float val = acc[mi][nj][r] + sh[r];
          vvb[(((size_t)(b * 256 + ocb + r)) << 12) + p] = __float2bfloat16(val);
        }
      }
    }
  } else {
    // ------------------------------ QK role (OC=32, IC=256)
    int p0 = (bx - 32) * 128;
    const bf16* In  = (by == 0) ? x4 : x3;
    const float* W  = (by == 0) ? wq : wk;
    const float* bi = (by == 0) ? bq : bk;
    bf16* Out       = (by == 0) ? qbf : kbf;
    const bf16* Inb = In + (size_t)b * 256 * 4096;

    f32x4 acc[2][2];
#pragma unroll
    for (int mi = 0; mi < 2; mi++)
#pragma unroll
      for (int nj = 0; nj < 2; nj++) acc[mi][nj] = (f32x4){0.f, 0.f, 0.f, 0.f};

    int aocl = t >> 3, akb = (t & 7) * 4;
    int sch = t >> 3, soct = sch >> 3, swi = sch & 7, spg = t & 7;

    for (int kc = 0; kc < 256; kc += 32) {
      __syncthreads();
      {
        const float* src = W + (size_t)aocl * 256 + kc + akb;
        float4 f0 = *(const float4*)(src);
        uint2 u = {pk2(f0.x, f0.y), pk2(f0.z, f0.w)};
        *(uint2*)&Al[aocl][akb] = u;
      }
      {
        const bf16* src = Inb + (size_t)(kc + sch) * 4096 + p0 + spg * 16;
        uint4 qv0 = *(const uint4*)src;
        uint4 qv1 = *(const uint4*)(src + 8);
        const unsigned short* qs0 = (const unsigned short*)&qv0;
        const unsigned short* qs1 = (const unsigned short*)&qv1;
#pragma unroll
        for (int j = 0; j < 8; j++) {
          int pix = spg * 16 + j;
          int col = (((soct ^ (pix >> 3)) & 3) << 3) | swi;
          *(unsigned short*)&Bl[pix][col] = qs0[j];
        }
#pragma unroll
        for (int j = 0; j < 8; j++) {
          int pix = spg * 16 + 8 + j;
          int col = (((soct ^ (pix >> 3)) & 3) << 3) | swi;
          *(unsigned short*)&Bl[pix][col] = qs1[j];
        }
      }
      __syncthreads();
      bf16x8 af[2], bvv[2];
#pragma unroll
      for (int mi = 0; mi < 2; mi++)
        af[mi] = *(const bf16x8*)&Al[mi * 16 + l16][quad * 8];
#pragma unroll
      for (int nj = 0; nj < 2; nj++) {
        int s = (nj * 2 + (l16 >> 3)) & 3;
        bvv[nj] = *(const bf16x8*)&Bl[w * 32 + nj * 16 + l16][(quad ^ s) * 8];
      }
#pragma unroll
      for (int mi = 0; mi < 2; mi++)
#pragma unroll
        for (int nj = 0; nj < 2; nj++)
          acc[mi][nj] = __builtin_amdgcn_mfma_f32_16x16x32_bf16(
              af[mi], bvv[nj], acc[mi][nj], 0, 0, 0);
    }

#pragma unroll
    for (int mi = 0; mi < 2; mi++) {
      int ocb = mi * 16 + quad * 4;
      float4 bs4 = *(const float4*)&bi[ocb];
      float bs[4] = {bs4.x, bs4.y, bs4.z, bs4.w};
#pragma unroll
      for (int nj = 0; nj < 2; nj++) {
        int p = p0 + w * 32 + nj * 16 + l16;
        float v0 = acc[mi][nj][0] + bs[0];
        float v1 = acc[mi][nj][1] + bs[1];
        float v2 = acc[mi][nj][2] + bs[2];
        float v3 = acc[mi][nj][3] + bs[3];
        uint2 u = {pk2(v0, v1), pk2(v2, v3)};
        *(uint2*)&Out[((size_t)(b * 4096) + p) * 32 + ocb] = u;
      }
    }
  }
}

// ------------------------------------------- MFMA flash attention + residual
// v10 structure + clamp removal (verified R13-R16: ~81-82us). FINAL.
// Signature: VGPR 60, occ ~40%, FETCH 14.4MB, conflicts 2.1M.
__global__ __launch_bounds__(512, 4) void k_attn_mfma(
    const bf16* __restrict__ qb, const bf16* __restrict__ kb,
    const bf16* __restrict__ vb, const float* __restrict__ x1,
    const float* __restrict__ gamma, float* __restrict__ out) {
  __shared__ __align__(16) bf16 Pl[2][64 * 128];   // 32 KB
  __shared__ float lsumw[8][64];

  int t = threadIdx.x;
  int w = t >> 6, lane = t & 63;
  int l16 = lane & 15, quad = lane >> 4;

  int lin = blockIdx.y * 128 + blockIdx.x;
  int xcd = lin & 7, slot = lin >> 3;
  int b = xcd >> 1;
  int chalf = xcd & 1;
  int q0 = slot * 64;

  const bf16* kbb = kb + (size_t)b * 4096 * 32;
  const bf16* vbb = vb + ((size_t)(b * 256 + chalf * 128)) * 4096;

  bf16x8 qf[4];
#pragma unroll
  for (int nj = 0; nj < 4; nj++)
    qf[nj] = *(const bf16x8*)(qb + ((size_t)(b * 4096 + q0 + nj * 16 + l16)) * 32 + quad * 8);

  f32x4 acc[4];
#pragma unroll
  for (int nj = 0; nj < 4; nj++) acc[nj] = (f32x4){0.f, 0.f, 0.f, 0.f};
  float lpart[4] = {0.f, 0.f, 0.f, 0.f};

  const bf16* kptr = kbb + ((size_t)(w * 16 + l16)) * 32 + quad * 8;
  const bf16* vptr = vbb + ((size_t)(w * 16 + l16)) * 4096 + quad * 8;

  int c16w = w * 2 + (quad >> 1);
  int off8 = (quad & 1) * 4;

  auto load_kv = [&](int j0, bf16x8& kf, bf16x8 vf[4]) {
    kf = *(const bf16x8*)(kptr + (size_t)j0 * 32);
#pragma unroll
    for (int kc = 0; kc < 4; kc++)
      vf[kc] = *(const bf16x8*)(vptr + j0 + kc * 32);
  };

  auto s_phase = [&](const bf16x8& kf, int pb) {
    bf16* P = Pl[pb];
    __builtin_amdgcn_s_setprio(1);
#pragma unroll
    for (int nj = 0; nj < 4; nj++) {
      f32x4 s = __builtin_amdgcn_mfma_f32_16x16x32_bf16(
          kf, qf[nj], (f32x4){0.f, 0.f, 0.f, 0.f}, 0, 0, 0);
      float p0f = __expf(s[0]);
      float p1f = __expf(s[1]);
      float p2f = __expf(s[2]);
      float p3f = __expf(s[3]);
      lpart[nj] += (p0f + p1f) + (p2f + p3f);
      int row = nj * 16 + l16;
      int c16 = c16w ^ (row & 15);
      uint2 u = {pk2(p0f, p1f), pk2(p2f, p3f)};
      *(uint2*)&P[row * 128 + c16 * 8 + off8] = u;
    }
    __builtin_amdgcn_s_setprio(0);
  };

  auto pv_phase = [&](const bf16x8 vf[4], int pb) {
    const bf16* P = Pl[pb];
#pragma unroll
    for (int kc = 0; kc < 4; kc++) {
      bf16x8 pf[4];
#pragma unroll
      for (int nj = 0; nj < 4; nj++) {
        int row = nj * 16 + l16;
        int c16 = (kc * 4 + quad) ^ (row & 15);
        pf[nj] = *(const bf16x8*)&P[row * 128 + c16 * 8];
      }
      __builtin_amdgcn_s_setprio(1);
#pragma unroll
      for (int nj = 0; nj < 4; nj++)
        acc[nj] = __builtin_amdgcn_mfma_f32_16x16x32_bf16(
            vf[kc], pf[nj], acc[nj], 0, 0, 0);
      __builtin_amdgcn_s_setprio(0);
    }
  };

  bf16x8 kfA, kfB, vfA[4], vfB[4];
  load_kv(0, kfA, vfA);
  s_phase(kfA, 0);

  for (int i = 0; i < 32; i += 2) {
    __syncthreads();
    if (i < 31) load_kv((i + 1) * 128, kfB, vfB);
    pv_phase(vfA, 0);
    if (i < 31) s_phase(kfB, 1);
    __syncthreads();
    if (i + 2 < 32) load_kv((i + 2) * 128, kfA, vfA);
    if (i + 1 < 32) pv_phase(vfB, 1);
    if (i + 2 < 32) s_phase(kfA, 0);
  }

#pragma unroll
  for (int nj = 0; nj < 4; nj++) {
    float v = lpart[nj];
    v += __shfl_xor(v, 16);
    v += __shfl_xor(v, 32);
    lpart[nj] = v;
  }
  if (lane < 16) {
#pragma unroll
    for (int nj = 0; nj < 4; nj++) lsumw[w][nj * 16 + lane] = lpart[nj];
  }
  __syncthreads();

  float gm = gamma[0];
#pragma unroll
  for (int nj = 0; nj < 4; nj++) {
    int ql = nj * 16 + l16;
    float ls = 0.f;
#pragma unroll
    for (int w8 = 0; w8 < 8; w8++) ls += lsumw[w8][ql];
    float gl = gm / ls;
    int cb = chalf * 128 + w * 16 + quad * 4;
#pragma unroll
    for (int r = 0; r < 4; r++) {
      size_t gidx = (((size_t)(b * 256 + cb + r)) << 12) + q0 + ql;
      out[gidx] = gl * acc[nj][r] + x1[gidx];
    }
  }
}

// ------------------------------------------------------------------- launcher
extern "C" void kernel_launch(void* const* d_in, const int* in_sizes, int n_in,
                              void* d_out, int out_size, void* d_ws, size_t ws_size,
                              hipStream_t stream) {
  const float* x1    = (const float*)d_in[0];
  const float* x2    = (const float*)d_in[1];
  const float* w1_dw = (const float*)d_in[2];
  const float* b1_dw = (const float*)d_in[3];
  const float* w1_pw = (const float*)d_in[4];
  const float* b1_pw = (const float*)d_in[5];
  const float* bn1_g = (const float*)d_in[6];
  const float* bn1_b = (const float*)d_in[7];
  const float* bn1_m = (const float*)d_in[8];
  const float* bn1_v = (const float*)d_in[9];
  const float* w2_dw = (const float*)d_in[10];
  const float* b2_dw = (const float*)d_in[11];
  const float* w2_pw = (const float*)d_in[12];
  const float* b2_pw = (const float*)d_in[13];
  const float* bn2_g = (const float*)d_in[14];
  const float* bn2_b = (const float*)d_in[15];
  const float* bn2_m = (const float*)d_in[16];
  const float* bn2_v = (const float*)d_in[17];
  const float* wq    = (const float*)d_in[18];
  const float* bq    = (const float*)d_in[19];
  const float* wk    = (const float*)d_in[20];
  const float* bk    = (const float*)d_in[21];
  const float* wv    = (const float*)d_in[22];
  const float* bv    = (const float*)d_in[23];
  const float* gamma = (const float*)d_in[24];

  // ws layout (bf16 units): h1 8.4M | h2 8.4M | x3 4.2M | x4 4.2M |
  // qb .5M | kb .5M | v 4.2M  -> 30.4M elems = 60.8 MB.
  // w1b/w2b live in the FRONT of the v region (written by dwconv3's wcvt
  // role, consumed by pw2, then overwritten by qkv's V role).
  bf16* wsb = (bf16*)d_ws;
  bf16* h1  = wsb;
  bf16* h2  = wsb + 8388608;
  bf16* x3  = wsb + 16777216;
  bf16* x4  = wsb + 20971520;
  bf16* qbf = wsb + 25165824;
  bf16* kbf = wsb + 25690112;
  bf16* vvb = wsb + 26214400;
  bf16* w1b = vvb;
  bf16* w2b = vvb + 131072;

  k_dwconv3<<<dim3(256, 5), 256, 0, stream>>>(x1, x2, w1_dw, b1_dw, w2_dw, b2_dw,
                                              w1_pw, w2_pw, h1, h2, w1b, w2b);
  k_gemm_pw2<<<dim3(32, 2, 8), 256, 0, stream>>>(h1, h2, w1b, w2b, b1_pw, b2_pw,
                                                 bn1_g, bn1_b, bn1_m, bn1_v,
                                                 bn2_g, bn2_b, bn2_m, bn2_v, x3, x4);
  k_gemm_qkv<<<dim3(64, 2, 4), 256, 0, stream>>>(x3, x4, wv, bv, wq, wk, bq, bk,
                                                 vvb, qbf, kbf);
  k_attn_mfma<<<dim3(128, 4), 512, 0, stream>>>(qbf, kbf, vvb, x1, gamma, (float*)d_out);
}